// Round 3
// baseline (109.655 us; speedup 1.0000x reference)
//
#include <hip/hip_runtime.h>
#include <stdint.h>

typedef unsigned short ushort_t;
typedef __bf16 bf16x8 __attribute__((ext_vector_type(8)));
typedef float f32x4 __attribute__((ext_vector_type(4)));
typedef unsigned short u16x8 __attribute__((ext_vector_type(8)));

#define TAU_F 0.07f
#define C2F 20.60992915555662f   // log2(e)/tau
#define INV_TAU 14.285714285714286f

#if __has_builtin(__builtin_amdgcn_exp2f)
#define EXP2F(x) __builtin_amdgcn_exp2f(x)   // single v_exp_f32
#else
#define EXP2F(x) exp2f(x)                    // OCML fallback
#endif

// ---- workspace layout (bytes) ----
#define A_OFF     0u          // bf16 matrix: 8192*128*2 = 2097152
#define LSUM_OFF  2097152u    // lsum partials: 8 slices * 8192 * 4 = 262144
#define SPART_OFF 2359296u    // per-block class-sum partials: 256*1280*4 = 1310720
#define CPART_OFF 3670016u    // per-block class-count partials: 256*16*4 = 16384
#define S_OFF     3686400u    // reduced class sums: 10*128*4 (padded)
#define CNT_OFF   3691520u    // reduced class counts: 16*4
#define CBLK_OFF  3691584u    // per-block (loss,anchors): 2048*2*4 = 16384

__device__ __forceinline__ ushort_t f2bf(float x) {
  uint32_t u = __float_as_uint(x);
  u += 0x7FFFu + ((u >> 16) & 1u);   // round-to-nearest-even
  return (ushort_t)(u >> 16);
}

__device__ __forceinline__ void gll16(const void* g, void* l) {
  // C-style casts: the only cast form clang accepts across address spaces (CK pattern)
  __builtin_amdgcn_global_load_lds(
      (const __attribute__((address_space(1))) uint32_t*)g,
      (__attribute__((address_space(3))) uint32_t*)l, 16, 0, 0);
}

// ---------------------------------------------------------------------------
// Kernel 1: fp32 -> bf16 convert + per-block class sums / counts
// grid 256 x 256 ; block b handles rows [b*32, b*32+32)
// ---------------------------------------------------------------------------
__global__ __launch_bounds__(256) void k_prep(const float* __restrict__ emb,
                                              const int* __restrict__ labels,
                                              ushort_t* __restrict__ abf,
                                              float* __restrict__ spart,
                                              int* __restrict__ cpart) {
  __shared__ float ssh[1280];
  __shared__ int csh[16];
  const int tid = threadIdx.x, b = blockIdx.x;
  for (int i = tid; i < 1280; i += 256) ssh[i] = 0.f;
  if (tid < 16) csh[tid] = 0;
  __syncthreads();

  const int r = b * 32 + (tid >> 3);
  const int c0 = (tid & 7) * 16;
  const int lab = labels[r];
  const float4* src = (const float4*)(emb + (size_t)r * 128 + c0);
  float v[16];
#pragma unroll
  for (int q = 0; q < 4; ++q) {
    float4 f = src[q];
    v[q * 4 + 0] = f.x; v[q * 4 + 1] = f.y; v[q * 4 + 2] = f.z; v[q * 4 + 3] = f.w;
  }
  u16x8 o0, o1;
#pragma unroll
  for (int k = 0; k < 8; ++k) { o0[k] = f2bf(v[k]); o1[k] = f2bf(v[8 + k]); }
  *(u16x8*)(abf + (size_t)r * 128 + c0) = o0;
  *(u16x8*)(abf + (size_t)r * 128 + c0 + 8) = o1;

#pragma unroll
  for (int k = 0; k < 16; ++k) atomicAdd(&ssh[lab * 128 + c0 + k], v[k]);
  if (c0 == 0) atomicAdd(&csh[lab], 1);
  __syncthreads();

  for (int i = tid; i < 1280; i += 256) spart[(size_t)b * 1280 + i] = ssh[i];
  if (tid < 16) cpart[b * 16 + tid] = csh[tid];
}

// ---------------------------------------------------------------------------
// Kernel 2: reduce class-sum / count partials. grid 5 x 256 (1280 threads)
// ---------------------------------------------------------------------------
__global__ __launch_bounds__(256) void k_reduce_s(const float* __restrict__ spart,
                                                  const int* __restrict__ cpart,
                                                  float* __restrict__ S,
                                                  int* __restrict__ cnt) {
  const int i = blockIdx.x * 256 + threadIdx.x;
  if (i < 1280) {
    float s = 0.f;
    for (int b = 0; b < 256; ++b) s += spart[(size_t)b * 1280 + i];
    S[i] = s;
  }
  if (i < 16) {
    int c = 0;
    for (int b = 0; b < 256; ++b) c += cpart[b * 16 + i];
    cnt[i] = c;
  }
}

// ---------------------------------------------------------------------------
// Kernel 3 (main): bf16 MFMA gemm_bt(E,E) fused with fixed-max exp-sum.
// grid 256 blocks x 512 threads. Block = 256 rows x 1024 cols, K=128 in regs.
// LDS: A panel 64KB (swizzled, loaded once) + 2 x 32KB B double-buffer.
// Fixed-max LSE: cos-sim <= 1 exactly, so exp((d-1)/tau) needs no running max.
// ---------------------------------------------------------------------------
__global__ __launch_bounds__(512, 2) void k_main(const ushort_t* __restrict__ abf,
                                                 float* __restrict__ lsum_out) {
  __shared__ __attribute__((aligned(16))) char lds[131072];
  const int tid = threadIdx.x;
  const int lane = tid & 63;
  const int wave = tid >> 6;       // 0..7
  const int lo = lane & 15, hi = lane >> 4;
  const int wr = wave >> 1, wc = wave & 1;   // 4 row groups x 2 col groups
  const int band = blockIdx.x & 31;
  const int slice = blockIdx.x >> 5;
  const int row0 = band * 256;
  const int col0 = slice * 1024;

  // ---- stage A panel (64KB). LDS image is XOR-swizzled via pre-swizzled
  // global source (global_load_lds dest is linear: base + lane*16, rule 21).
#pragma unroll
  for (int i = 0; i < 8; ++i) {
    int p = i * 512 + tid;
    int r = p >> 4, s = p & 15;
    const ushort_t* g = abf + (size_t)(row0 + r) * 128 + ((s ^ (r & 7)) << 3);
    gll16(g, lds + (size_t)(i * 512 + wave * 64) * 16);
  }
  // ---- stage B tile 0 into buf0
#pragma unroll
  for (int i = 0; i < 4; ++i) {
    int p = i * 512 + tid;
    int r = p >> 4, s = p & 15;
    const ushort_t* g = abf + (size_t)(col0 + r) * 128 + ((s ^ (r & 7)) << 3);
    gll16(g, lds + 65536 + (size_t)(i * 512 + wave * 64) * 16);
  }
  asm volatile("s_waitcnt vmcnt(0)" ::: "memory");
  __builtin_amdgcn_s_barrier();
  __builtin_amdgcn_sched_barrier(0);

  // ---- A fragments -> registers (held for all 8 column tiles)
  // kb is a BYTE offset: K-slice ks, lane quarter hi -> elems ks*32+hi*8
  bf16x8 af[4][4];
#pragma unroll
  for (int mf = 0; mf < 4; ++mf) {
#pragma unroll
    for (int ks = 0; ks < 4; ++ks) {
      int r = wr * 64 + mf * 16 + lo;
      int kb = ks * 64 + hi * 16;
      af[mf][ks] = *(const bf16x8*)(lds + r * 256 + (kb ^ ((r & 7) << 4)));
    }
  }

  float lsum[4][4];
#pragma unroll
  for (int mf = 0; mf < 4; ++mf)
#pragma unroll
    for (int q = 0; q < 4; ++q) lsum[mf][q] = 0.f;

  int cur = 0;
  for (int t = 0; t < 8; ++t) {
    // prefetch next tile into the other buffer (issue early, drain late)
    if (t < 7) {
      const int tc0 = col0 + (t + 1) * 128;
      char* buf = lds + 65536 + (cur ^ 1) * 32768;
#pragma unroll
      for (int i = 0; i < 4; ++i) {
        int p = i * 512 + tid;
        int r = p >> 4, s = p & 15;
        const ushort_t* g = abf + (size_t)(tc0 + r) * 128 + ((s ^ (r & 7)) << 3);
        gll16(g, buf + (size_t)(i * 512 + wave * 64) * 16);
      }
    }
    // ---- compute tile t
    const char* bb = lds + 65536 + cur * 32768;
    f32x4 acc[4][4];
    const f32x4 z = {0.f, 0.f, 0.f, 0.f};
#pragma unroll
    for (int mf = 0; mf < 4; ++mf)
#pragma unroll
      for (int nf = 0; nf < 4; ++nf) acc[mf][nf] = z;

#pragma unroll
    for (int ks = 0; ks < 4; ++ks) {
      bf16x8 bfr[4];
#pragma unroll
      for (int nf = 0; nf < 4; ++nf) {
        int c = wc * 64 + nf * 16 + lo;
        int kb = ks * 64 + hi * 16;
        bfr[nf] = *(const bf16x8*)(bb + c * 256 + (kb ^ ((c & 7) << 4)));
      }
#pragma unroll
      for (int mf = 0; mf < 4; ++mf)
#pragma unroll
        for (int nf = 0; nf < 4; ++nf)
          acc[mf][nf] = __builtin_amdgcn_mfma_f32_16x16x32_bf16(
              af[mf][ks], bfr[nf], acc[mf][nf], 0, 0, 0);
    }

    // ---- epilogue: lsum += exp((d-1)/tau) = exp2(d*C2 - C2); mask diagonal.
    const int gr0 = row0 + wr * 64;
    const int gc0 = col0 + t * 128 + wc * 64;
    const bool diag = (gr0 == gc0);   // 64-aligned ranges: identical or disjoint
#pragma unroll
    for (int mf = 0; mf < 4; ++mf) {
#pragma unroll
      for (int nf = 0; nf < 4; ++nf) {
#pragma unroll
        for (int q = 0; q < 4; ++q) {
          float d = acc[mf][nf][q];
          float e = EXP2F(fmaf(d, C2F, -C2F));
          if (diag && (mf * 16 + hi * 4 + q) == (nf * 16 + lo)) e = 0.f;
          lsum[mf][q] += e;
        }
      }
    }

    asm volatile("s_waitcnt vmcnt(0)" ::: "memory");
    __builtin_amdgcn_s_barrier();
    __builtin_amdgcn_sched_barrier(0);
    cur ^= 1;
  }

  // ---- reduce lsum across the 16-lane column group (bits 0..3 = lo)
#pragma unroll
  for (int mf = 0; mf < 4; ++mf) {
#pragma unroll
    for (int q = 0; q < 4; ++q) {
      float v = lsum[mf][q];
      v += __shfl_xor(v, 1);
      v += __shfl_xor(v, 2);
      v += __shfl_xor(v, 4);
      v += __shfl_xor(v, 8);
      lsum[mf][q] = v;
    }
  }
  // combine the two col-half waves sharing rows, write per-row partials
  float* lsh = (float*)lds;   // reuse A region (A consumed into registers)
  __syncthreads();
  if (lo == 0 && wc == 0) {
#pragma unroll
    for (int mf = 0; mf < 4; ++mf)
#pragma unroll
      for (int q = 0; q < 4; ++q)
        lsh[wr * 64 + mf * 16 + hi * 4 + q] = lsum[mf][q];
  }
  __syncthreads();
  if (lo == 0 && wc == 1) {
#pragma unroll
    for (int mf = 0; mf < 4; ++mf)
#pragma unroll
      for (int q = 0; q < 4; ++q)
        lsh[wr * 64 + mf * 16 + hi * 4 + q] += lsum[mf][q];
  }
  __syncthreads();
  if (tid < 256) lsum_out[(size_t)slice * 8192 + row0 + tid] = lsh[tid];
}

// ---------------------------------------------------------------------------
// Kernel 4: per-row finalize. One wave per row. grid 2048 x 256.
// pos_sum via class-sum trick: sum_{p!=i,same label} sim = (e_i.S_c - e_i.e_i)/tau
// ---------------------------------------------------------------------------
__global__ __launch_bounds__(256) void k_row(const float* __restrict__ emb,
                                             const int* __restrict__ labels,
                                             const float* __restrict__ S,
                                             const int* __restrict__ cnt,
                                             const float* __restrict__ lsum_part,
                                             float* __restrict__ cblk) {
  const int tid = threadIdx.x;
  const int lane = tid & 63;
  const int w = tid >> 6;                 // 0..3
  const int i = blockIdx.x * 4 + w;       // row
  const int lab = labels[i];
  float2 a = ((const float2*)(emb + (size_t)i * 128))[lane];
  float2 s = ((const float2*)(S + (size_t)lab * 128))[lane];
  float pd = a.x * s.x + a.y * s.y;       // e_i . S_class
  float sd = a.x * a.x + a.y * a.y;       // e_i . e_i
#pragma unroll
  for (int m = 1; m < 64; m <<= 1) { pd += __shfl_xor(pd, m); sd += __shfl_xor(sd, m); }
  float ls = (lane < 8) ? lsum_part[(size_t)lane * 8192 + i] : 0.f;
  ls += __shfl_xor(ls, 1); ls += __shfl_xor(ls, 2); ls += __shfl_xor(ls, 4);

  float loss = 0.f, anc = 0.f;
  if (lane == 0) {
    int np = cnt[lab] - 1;
    float logden = logf(ls) + INV_TAU;   // fixed-max LSE: sim bound = 1/tau
    if (np > 0) {
      loss = logden - (pd - sd) / (TAU_F * (float)np);
      anc = 1.f;
    }
  }
  __shared__ float red[8];
  if (lane == 0) { red[w * 2] = loss; red[w * 2 + 1] = anc; }
  __syncthreads();
  if (tid == 0) {
    cblk[(size_t)blockIdx.x * 2]     = red[0] + red[2] + red[4] + red[6];
    cblk[(size_t)blockIdx.x * 2 + 1] = red[1] + red[3] + red[5] + red[7];
  }
}

// ---------------------------------------------------------------------------
// Kernel 5: final scalar. 1 block.
// ---------------------------------------------------------------------------
__global__ __launch_bounds__(256) void k_fin(const float* __restrict__ cblk,
                                             float* __restrict__ out) {
  const int tid = threadIdx.x;
  float sl = 0.f, sa = 0.f;
  for (int i = tid; i < 2048; i += 256) { sl += cblk[i * 2]; sa += cblk[i * 2 + 1]; }
  __shared__ float shl[256], sha[256];
  shl[tid] = sl; sha[tid] = sa;
  __syncthreads();
  for (int s = 128; s > 0; s >>= 1) {
    if (tid < s) { shl[tid] += shl[tid + s]; sha[tid] += sha[tid + s]; }
    __syncthreads();
  }
  if (tid == 0) out[0] = shl[0] / fmaxf(sha[0], 1.0f);
}

// ---------------------------------------------------------------------------
extern "C" void kernel_launch(void* const* d_in, const int* in_sizes, int n_in,
                              void* d_out, int out_size, void* d_ws, size_t ws_size,
                              hipStream_t stream) {
  const float* emb = (const float*)d_in[0];
  const int* labels = (const int*)d_in[1];
  char* ws = (char*)d_ws;
  ushort_t* abf = (ushort_t*)(ws + A_OFF);
  float* lsum  = (float*)(ws + LSUM_OFF);
  float* spart = (float*)(ws + SPART_OFF);
  int*   cpart = (int*)(ws + CPART_OFF);
  float* S     = (float*)(ws + S_OFF);
  int*   cnt   = (int*)(ws + CNT_OFF);
  float* cblk  = (float*)(ws + CBLK_OFF);
  float* out   = (float*)d_out;

  hipLaunchKernelGGL(k_prep, dim3(256), dim3(256), 0, stream, emb, labels, abf, spart, cpart);
  hipLaunchKernelGGL(k_reduce_s, dim3(5), dim3(256), 0, stream, spart, cpart, S, cnt);
  hipLaunchKernelGGL(k_main, dim3(256), dim3(512), 0, stream, abf, lsum);
  hipLaunchKernelGGL(k_row, dim3(2048), dim3(256), 0, stream, emb, labels, S, cnt, lsum, cblk);
  hipLaunchKernelGGL(k_fin, dim3(1), dim3(256), 0, stream, cblk, out);
}

// Round 4
// 99.131 us; speedup vs baseline: 1.1062x; 1.1062x over previous
//
#include <hip/hip_runtime.h>
#include <stdint.h>

typedef unsigned short ushort_t;
typedef __bf16 bf16x8 __attribute__((ext_vector_type(8)));
typedef float f32x4 __attribute__((ext_vector_type(4)));
typedef unsigned short u16x8 __attribute__((ext_vector_type(8)));

#define TAU_F 0.07f
#define C2F 20.60992915555662f   // log2(e)/tau
#define INV_TAU 14.285714285714286f

#if __has_builtin(__builtin_amdgcn_exp2f)
#define EXP2F(x) __builtin_amdgcn_exp2f(x)   // single v_exp_f32
#else
#define EXP2F(x) exp2f(x)                    // OCML fallback
#endif

// ---- workspace layout (bytes) ----
#define A_OFF     0u          // bf16 matrix: 8192*128*2 = 2097152
#define LSUM_OFF  2097152u    // lsum partials: 8 slices * 8192 * 4 = 262144
#define S_OFF     2359296u    // class sums: 10*128*4 = 5120 (atomic-accumulated)
#define CNT_OFF   2364416u    // class counts: 16*4 = 64
#define CBLK_OFF  2364480u    // per-block (loss,anchors): 2048*2*4 = 16384

__device__ __forceinline__ ushort_t f2bf(float x) {
  uint32_t u = __float_as_uint(x);
  u += 0x7FFFu + ((u >> 16) & 1u);   // round-to-nearest-even
  return (ushort_t)(u >> 16);
}

__device__ __forceinline__ void gll16(const void* g, void* l) {
  // C-style casts: the only cast form clang accepts across address spaces
  __builtin_amdgcn_global_load_lds(
      (const __attribute__((address_space(1))) uint32_t*)g,
      (__attribute__((address_space(3))) uint32_t*)l, 16, 0, 0);
}

// ---------------------------------------------------------------------------
// Kernel 1: fp32 -> bf16 convert + class sums/counts (LDS reduce -> global
// atomicAdd into S/cnt, which kernel_launch zeroed via hipMemsetAsync).
// grid 256 x 256 ; block b handles rows [b*32, b*32+32)
// ---------------------------------------------------------------------------
__global__ __launch_bounds__(256) void k_prep(const float* __restrict__ emb,
                                              const int* __restrict__ labels,
                                              ushort_t* __restrict__ abf,
                                              float* __restrict__ S,
                                              int* __restrict__ cnt) {
  __shared__ float ssh[1280];
  __shared__ int csh[16];
  const int tid = threadIdx.x, b = blockIdx.x;
  for (int i = tid; i < 1280; i += 256) ssh[i] = 0.f;
  if (tid < 16) csh[tid] = 0;
  __syncthreads();

  const int r = b * 32 + (tid >> 3);
  const int c0 = (tid & 7) * 16;
  const int lab = labels[r];
  const float4* src = (const float4*)(emb + (size_t)r * 128 + c0);
  float v[16];
#pragma unroll
  for (int q = 0; q < 4; ++q) {
    float4 f = src[q];
    v[q * 4 + 0] = f.x; v[q * 4 + 1] = f.y; v[q * 4 + 2] = f.z; v[q * 4 + 3] = f.w;
  }
  u16x8 o0, o1;
#pragma unroll
  for (int k = 0; k < 8; ++k) { o0[k] = f2bf(v[k]); o1[k] = f2bf(v[8 + k]); }
  *(u16x8*)(abf + (size_t)r * 128 + c0) = o0;
  *(u16x8*)(abf + (size_t)r * 128 + c0 + 8) = o1;

#pragma unroll
  for (int k = 0; k < 16; ++k) atomicAdd(&ssh[lab * 128 + c0 + k], v[k]);
  if (c0 == 0) atomicAdd(&csh[lab], 1);
  __syncthreads();

  // global accumulation (device-scope atomics, S/cnt pre-zeroed)
  for (int i = tid; i < 1280; i += 256) atomicAdd(&S[i], ssh[i]);
  if (tid < 16 && csh[tid] != 0) atomicAdd(&cnt[tid], csh[tid]);
}

// ---------------------------------------------------------------------------
// Kernel 2 (main): bf16 MFMA gemm_bt(E,E) fused with fixed-max exp-sum.
// grid 256 blocks x 512 threads. Block = 256 rows x 1024 cols, K=128 in regs.
// LDS: A panel 64KB (swizzled, loaded once) + 2 x 32KB B double-buffer.
// Fixed-max LSE: cos-sim <= 1 exactly, so exp((d-1)/tau) needs no running max.
// ---------------------------------------------------------------------------
__global__ __launch_bounds__(512, 2) void k_main(const ushort_t* __restrict__ abf,
                                                 float* __restrict__ lsum_out) {
  __shared__ __attribute__((aligned(16))) char lds[131072];
  const int tid = threadIdx.x;
  const int lane = tid & 63;
  const int wave = tid >> 6;       // 0..7
  const int lo = lane & 15, hi = lane >> 4;
  const int wr = wave >> 1, wc = wave & 1;   // 4 row groups x 2 col groups
  const int band = blockIdx.x & 31;
  const int slice = blockIdx.x >> 5;
  const int row0 = band * 256;
  const int col0 = slice * 1024;

  // ---- stage A panel (64KB). LDS image is XOR-swizzled via pre-swizzled
  // global source (global_load_lds dest is linear: base + lane*16, rule 21).
#pragma unroll
  for (int i = 0; i < 8; ++i) {
    int p = i * 512 + tid;
    int r = p >> 4, s = p & 15;
    const ushort_t* g = abf + (size_t)(row0 + r) * 128 + ((s ^ (r & 7)) << 3);
    gll16(g, lds + (size_t)(i * 512 + wave * 64) * 16);
  }
  // ---- stage B tile 0 into buf0
#pragma unroll
  for (int i = 0; i < 4; ++i) {
    int p = i * 512 + tid;
    int r = p >> 4, s = p & 15;
    const ushort_t* g = abf + (size_t)(col0 + r) * 128 + ((s ^ (r & 7)) << 3);
    gll16(g, lds + 65536 + (size_t)(i * 512 + wave * 64) * 16);
  }
  asm volatile("s_waitcnt vmcnt(0)" ::: "memory");
  __builtin_amdgcn_s_barrier();
  __builtin_amdgcn_sched_barrier(0);

  // ---- A fragments -> registers (held for all 8 column tiles)
  // kb is a BYTE offset: K-slice ks, lane quarter hi -> elems ks*32+hi*8
  bf16x8 af[4][4];
#pragma unroll
  for (int mf = 0; mf < 4; ++mf) {
#pragma unroll
    for (int ks = 0; ks < 4; ++ks) {
      int r = wr * 64 + mf * 16 + lo;
      int kb = ks * 64 + hi * 16;
      af[mf][ks] = *(const bf16x8*)(lds + r * 256 + (kb ^ ((r & 7) << 4)));
    }
  }

  float lsum[4][4];
#pragma unroll
  for (int mf = 0; mf < 4; ++mf)
#pragma unroll
    for (int q = 0; q < 4; ++q) lsum[mf][q] = 0.f;

  int cur = 0;
  for (int t = 0; t < 8; ++t) {
    // prefetch next tile into the other buffer (issue early, drain late:
    // a full compute phase (~1000+ cyc) covers the L2-hit staging latency)
    if (t < 7) {
      const int tc0 = col0 + (t + 1) * 128;
      char* buf = lds + 65536 + (cur ^ 1) * 32768;
#pragma unroll
      for (int i = 0; i < 4; ++i) {
        int p = i * 512 + tid;
        int r = p >> 4, s = p & 15;
        const ushort_t* g = abf + (size_t)(tc0 + r) * 128 + ((s ^ (r & 7)) << 3);
        gll16(g, buf + (size_t)(i * 512 + wave * 64) * 16);
      }
    }
    // ---- compute tile t
    const char* bb = lds + 65536 + cur * 32768;
    f32x4 acc[4][4];
    const f32x4 z = {0.f, 0.f, 0.f, 0.f};
#pragma unroll
    for (int mf = 0; mf < 4; ++mf)
#pragma unroll
      for (int nf = 0; nf < 4; ++nf) acc[mf][nf] = z;

#pragma unroll
    for (int ks = 0; ks < 4; ++ks) {
      bf16x8 bfr[4];
#pragma unroll
      for (int nf = 0; nf < 4; ++nf) {
        int c = wc * 64 + nf * 16 + lo;
        int kb = ks * 64 + hi * 16;
        bfr[nf] = *(const bf16x8*)(bb + c * 256 + (kb ^ ((c & 7) << 4)));
      }
#pragma unroll
      for (int mf = 0; mf < 4; ++mf)
#pragma unroll
        for (int nf = 0; nf < 4; ++nf)
          acc[mf][nf] = __builtin_amdgcn_mfma_f32_16x16x32_bf16(
              af[mf][ks], bfr[nf], acc[mf][nf], 0, 0, 0);
    }

    // ---- epilogue: lsum += exp((d-1)/tau) = exp2(d*C2 - C2); mask diagonal.
    const int gr0 = row0 + wr * 64;
    const int gc0 = col0 + t * 128 + wc * 64;
    const bool diag = (gr0 == gc0);   // 64-aligned ranges: identical or disjoint
#pragma unroll
    for (int mf = 0; mf < 4; ++mf) {
#pragma unroll
      for (int nf = 0; nf < 4; ++nf) {
#pragma unroll
        for (int q = 0; q < 4; ++q) {
          float d = acc[mf][nf][q];
          float e = EXP2F(fmaf(d, C2F, -C2F));
          if (diag && (mf * 16 + hi * 4 + q) == (nf * 16 + lo)) e = 0.f;
          lsum[mf][q] += e;
        }
      }
    }

    asm volatile("s_waitcnt vmcnt(0)" ::: "memory");
    __builtin_amdgcn_s_barrier();
    __builtin_amdgcn_sched_barrier(0);
    cur ^= 1;
  }

  // ---- reduce lsum across the 16-lane column group (bits 0..3 = lo)
#pragma unroll
  for (int mf = 0; mf < 4; ++mf) {
#pragma unroll
    for (int q = 0; q < 4; ++q) {
      float v = lsum[mf][q];
      v += __shfl_xor(v, 1);
      v += __shfl_xor(v, 2);
      v += __shfl_xor(v, 4);
      v += __shfl_xor(v, 8);
      lsum[mf][q] = v;
    }
  }
  // combine the two col-half waves sharing rows, write per-row partials
  float* lsh = (float*)lds;   // reuse A region (A consumed into registers)
  __syncthreads();
  if (lo == 0 && wc == 0) {
#pragma unroll
    for (int mf = 0; mf < 4; ++mf)
#pragma unroll
      for (int q = 0; q < 4; ++q)
        lsh[wr * 64 + mf * 16 + hi * 4 + q] = lsum[mf][q];
  }
  __syncthreads();
  if (lo == 0 && wc == 1) {
#pragma unroll
    for (int mf = 0; mf < 4; ++mf)
#pragma unroll
      for (int q = 0; q < 4; ++q)
        lsh[wr * 64 + mf * 16 + hi * 4 + q] += lsum[mf][q];
  }
  __syncthreads();
  if (tid < 256) lsum_out[(size_t)slice * 8192 + row0 + tid] = lsh[tid];
}

// ---------------------------------------------------------------------------
// Kernel 3: per-row finalize. One wave per row. grid 2048 x 256.
// pos_sum via class-sum trick: sum_{p!=i,same label} sim = (e_i.S_c - e_i.e_i)/tau
// ---------------------------------------------------------------------------
__global__ __launch_bounds__(256) void k_row(const float* __restrict__ emb,
                                             const int* __restrict__ labels,
                                             const float* __restrict__ S,
                                             const int* __restrict__ cnt,
                                             const float* __restrict__ lsum_part,
                                             float* __restrict__ cblk) {
  const int tid = threadIdx.x;
  const int lane = tid & 63;
  const int w = tid >> 6;                 // 0..3
  const int i = blockIdx.x * 4 + w;       // row
  const int lab = labels[i];
  float2 a = ((const float2*)(emb + (size_t)i * 128))[lane];
  float2 s = ((const float2*)(S + (size_t)lab * 128))[lane];
  float pd = a.x * s.x + a.y * s.y;       // e_i . S_class
  float sd = a.x * a.x + a.y * a.y;       // e_i . e_i
#pragma unroll
  for (int m = 1; m < 64; m <<= 1) { pd += __shfl_xor(pd, m); sd += __shfl_xor(sd, m); }
  float ls = (lane < 8) ? lsum_part[(size_t)lane * 8192 + i] : 0.f;
  ls += __shfl_xor(ls, 1); ls += __shfl_xor(ls, 2); ls += __shfl_xor(ls, 4);

  float loss = 0.f, anc = 0.f;
  if (lane == 0) {
    int np = cnt[lab] - 1;
    float logden = logf(ls) + INV_TAU;   // fixed-max LSE: sim bound = 1/tau
    if (np > 0) {
      loss = logden - (pd - sd) / (TAU_F * (float)np);
      anc = 1.f;
    }
  }
  __shared__ float red[8];
  if (lane == 0) { red[w * 2] = loss; red[w * 2 + 1] = anc; }
  __syncthreads();
  if (tid == 0) {
    cblk[(size_t)blockIdx.x * 2]     = red[0] + red[2] + red[4] + red[6];
    cblk[(size_t)blockIdx.x * 2 + 1] = red[1] + red[3] + red[5] + red[7];
  }
}

// ---------------------------------------------------------------------------
// Kernel 4: final scalar. 1 block.
// ---------------------------------------------------------------------------
__global__ __launch_bounds__(256) void k_fin(const float* __restrict__ cblk,
                                             float* __restrict__ out) {
  const int tid = threadIdx.x;
  float sl = 0.f, sa = 0.f;
  for (int i = tid; i < 2048; i += 256) { sl += cblk[i * 2]; sa += cblk[i * 2 + 1]; }
  __shared__ float shl[256], sha[256];
  shl[tid] = sl; sha[tid] = sa;
  __syncthreads();
  for (int s = 128; s > 0; s >>= 1) {
    if (tid < s) { shl[tid] += shl[tid + s]; sha[tid] += sha[tid + s]; }
    __syncthreads();
  }
  if (tid == 0) out[0] = shl[0] / fmaxf(sha[0], 1.0f);
}

// ---------------------------------------------------------------------------
extern "C" void kernel_launch(void* const* d_in, const int* in_sizes, int n_in,
                              void* d_out, int out_size, void* d_ws, size_t ws_size,
                              hipStream_t stream) {
  const float* emb = (const float*)d_in[0];
  const int* labels = (const int*)d_in[1];
  char* ws = (char*)d_ws;
  ushort_t* abf = (ushort_t*)(ws + A_OFF);
  float* lsum  = (float*)(ws + LSUM_OFF);
  float* S     = (float*)(ws + S_OFF);
  int*   cnt   = (int*)(ws + CNT_OFF);
  float* cblk  = (float*)(ws + CBLK_OFF);
  float* out   = (float*)d_out;

  // zero the atomic-accumulated S (1280 f32) + cnt (16 i32) region
  hipMemsetAsync(ws + S_OFF, 0, 5184, stream);
  hipLaunchKernelGGL(k_prep, dim3(256), dim3(256), 0, stream, emb, labels, abf, S, cnt);
  hipLaunchKernelGGL(k_main, dim3(256), dim3(512), 0, stream, abf, lsum);
  hipLaunchKernelGGL(k_row, dim3(2048), dim3(256), 0, stream, emb, labels, S, cnt, lsum, cblk);
  hipLaunchKernelGGL(k_fin, dim3(1), dim3(256), 0, stream, cblk, out);
}